// Round 11
// baseline (11148.755 us; speedup 1.0000x reference)
//
#include <hip/hip_runtime.h>
#include <cstdint>
#include <cstddef>

// ---------------------------------------------------------------------------
// CTC-CRF BLSTM pipeline for MI355X.  B=64 T=1024 IDIM=120 HDIM=320 K=72
// den == 0 analytically; batch sort is a no-op under the batch mean. Skipped.
//
// R19 deltas vs R18 (8.51 ms, scan 289us/chunk, VGPR_Count STILL 128):
//  - R18 proved the allocator caps at 128 VGPRs regardless of
//    amdgpu_num_vgpr(256) -> the 200-dword weight array kept ~100
//    dwords/thread in scratch (L2-served, invisible in FETCH_SIZE).
//  - New strategy: design for <=128 regs instead of fighting for 256.
//    1024-thread layout needs only 100 weight dwords/thread (+ ~25
//    working) = 125 <= 128. R17 already verified this exact kernel
//    (passed, absmax 0) but launch_bounds(1024,4) is a MINIMUM-waves
//    hint -> allocator went to 8 waves/EU = 64 VGPRs = spill.
//    amdgpu_waves_per_eu(4,4) pins exactly 4 waves/EU -> 128 VGPRs.
//  - Verification bit: VGPR_Count must read 128 (not 64).
// ---------------------------------------------------------------------------

typedef _Float16 f16;
typedef _Float16 h2v   __attribute__((ext_vector_type(2)));
typedef _Float16 f16x4v __attribute__((ext_vector_type(4)));
typedef _Float16 f16x8 __attribute__((ext_vector_type(8)));
typedef float    f32x4 __attribute__((ext_vector_type(4)));
typedef uint32_t u32x4 __attribute__((ext_vector_type(4)));

#define NEGF (-1e30f)
#define CT 128

__device__ __forceinline__ int dot4i8(int a, int b, int c) {
#if __has_builtin(__builtin_amdgcn_sdot4)
  return __builtin_amdgcn_sdot4(a, b, c, false);
#else
  int s = c;
#pragma unroll
  for (int e = 0; e < 4; ++e)
    s += (int)(int8_t)(a >> (8 * e)) * (int)(int8_t)(b >> (8 * e));
  return s;
#endif
}

__device__ __forceinline__ float fast_rcp(float x) {
#if __has_builtin(__builtin_amdgcn_rcpf)
  return __builtin_amdgcn_rcpf(x);
#else
  return 1.f / x;
#endif
}
__device__ __forceinline__ float fsigm(float x) { return fast_rcp(1.f + __expf(-x)); }
__device__ __forceinline__ float ftanh(float x) { return 1.f - 2.f * fast_rcp(1.f + __expf(2.f * x)); }

__device__ __forceinline__ float fexp2(float x) {
#if __has_builtin(__builtin_amdgcn_exp2f)
  return __builtin_amdgcn_exp2f(x);
#else
  return exp2f(x);
#endif
}
__device__ __forceinline__ float flog2(float x) {
#if __has_builtin(__builtin_amdgcn_logf)
  return __builtin_amdgcn_logf(x);
#else
  return log2f(x);
#endif
}

__device__ __forceinline__ void stage16(f16* lds, const f16* g) {
#if __has_builtin(__builtin_amdgcn_global_load_lds)
  __builtin_amdgcn_global_load_lds(
      (const __attribute__((address_space(1))) uint32_t*)g,
      (__attribute__((address_space(3))) uint32_t*)lds, 16, 0, 0);
#else
  int lane = threadIdx.x & 63;
  *(f16x8*)&lds[lane * 8] = *(const f16x8*)g;
#endif
}

// ---------------------------- convert kernels ------------------------------

__global__ void conv_logits(const float* __restrict__ src, f16* __restrict__ dst) {
  int idx = blockIdx.x * 256 + threadIdx.x;      // < 65536*128
  int row = idx >> 7, k = idx & 127;
  dst[idx] = (f16)((k < 120) ? src[(size_t)row * 120 + k] : 0.f);
}

__global__ void conv_wt0(const float* __restrict__ w, f16* __restrict__ dst) {
  int idx = blockIdx.x * 256 + threadIdx.x;      // < 2560*128
  int n = idx >> 7, k = idx & 127;
  dst[idx] = (f16)((k < 120) ? w[(size_t)n * 120 + k] : 0.f);
}

__global__ void conv_copy(const float* __restrict__ src, f16* __restrict__ dst, int count) {
  int idx = blockIdx.x * 256 + threadIdx.x;
  if (idx < count) dst[idx] = (f16)src[idx];
}

__global__ void conv_wtl(const float* __restrict__ w, f16* __restrict__ dst) {
  int idx = blockIdx.x * 256 + threadIdx.x;      // < 128*640
  int n = idx / 640, k = idx % 640;
  dst[idx] = (f16)((n < 72) ? w[(size_t)n * 640 + k] : 0.f);
}

// per-row abs-max scales for Whh int8 quantization: s_r = rowmax/127.
// rows indexed (slot*1280 + r), slot = layer*2 + dir (6 slots).
__global__ void conv_scale(const float* __restrict__ whh0, const float* __restrict__ whh,
                           float* __restrict__ scales) {
  int row = blockIdx.x * 4 + (threadIdx.x >> 6);   // < 7680
  int lane = threadIdx.x & 63;
  int slot = row / 1280, r = row - slot * 1280;
  const float* src = (slot < 2) ? (whh0 + ((size_t)slot * 1280 + r) * 320)
                                : (whh  + ((size_t)(slot - 2) * 1280 + r) * 320);
  float m = 0.f;
  for (int k = lane; k < 320; k += 64) m = fmaxf(m, fabsf(src[k]));
#pragma unroll
  for (int o = 32; o; o >>= 1) m = fmaxf(m, __shfl_xor(m, o, 64));
  if (lane == 0) scales[row] = fmaxf(m, 1e-20f) * (1.f / 127.f);
}

// Whh -> int8 packed scan layout for 1024-thread WGs: word for
// (slot, i, j, t) holds row r = i*256 + (t>>2), cols k0..k0+3 with
// k0 = (t&3)*80 + j*4.  (Verified correct in R17: passed, absmax 0.)
__global__ void conv_wq(const float* __restrict__ whh0, const float* __restrict__ whh,
                        const float* __restrict__ scales, uint32_t* __restrict__ dst) {
  int o = blockIdx.x * 256 + threadIdx.x;          // < 6*5*20*1024 = 614400
  int t = o & 1023;
  int g = o >> 10;
  int j = g % 20;
  int g2 = g / 20;
  int i = g2 % 5;
  int slot = g2 / 5;
  int qi = t >> 2, kq = t & 3;
  int r = i * 256 + qi;
  int k0 = kq * 80 + j * 4;
  const float* src = (slot < 2) ? (whh0 + ((size_t)slot * 1280 + r) * 320)
                                : (whh  + ((size_t)(slot - 2) * 1280 + r) * 320);
  float s = scales[slot * 1280 + r];
  float rs = fast_rcp(s);
  uint32_t w = 0;
#pragma unroll
  for (int e = 0; e < 4; ++e) {
    float q = rintf(src[k0 + e] * rs);
    q = fminf(fmaxf(q, -127.f), 127.f);
    w |= ((uint32_t)(uint8_t)(int8_t)(int)q) << (8 * e);
  }
  dst[o] = w;
}

// --------------------- gather-GEMM for one time chunk ----------------------
__global__ __launch_bounds__(256)
void gemm_chunk(const f16* __restrict__ A, const f16* __restrict__ W,
                f16* __restrict__ gxc, const int* __restrict__ lens,
                int lda, int kTiles, int c0) {
  __shared__ __align__(16) f16 As[128 * 32];
  __shared__ __align__(16) f16 Ws[2][128 * 32];
  const int tid = threadIdx.x;
  const int lane = tid & 63, wid = tid >> 6;
  const int wm = wid >> 1, wn = wid & 1;
  const int dir = blockIdx.y >> 6, b = blockIdx.y & 63;
  const int n0 = blockIdx.x * 256;
  const int r_base = lane >> 2;                              // 0..15
  const int chs = ((((lane & 3) + (r_base >> 1)) & 3)) * 8;  // swizzled SRC k-chunk
  const int len = lens[b];

  f32x4 acc[4][8] = {};

  for (int kt = 0; kt < kTiles; ++kt) {
    const int k0 = kt * 32;
    __syncthreads();
#pragma unroll
    for (int hh = 0; hh < 2; ++hh) {
      const int c = wid * 2 + hh;
      const int j = c * 16 + r_base;                     // step within chunk
      const int s = c0 * CT + j;
      const int tt = dir ? ((s < len) ? (len - 1 - s) : s) : s;
      stage16(&As[c * 512], A + (size_t)(b * 1024 + tt) * lda + k0 + chs);
    }
#pragma unroll
    for (int hh = 0; hh < 4; ++hh) {
      const int c = wid * 4 + hh;                        // 0..15
      const int tile = c >> 3, cc = c & 7;
      stage16(&Ws[tile][cc * 512],
              W + (size_t)(dir * 1280 + n0 + tile * 128 + cc * 16 + r_base) * lda + k0 + chs);
    }
    __syncthreads();

    const int q = lane >> 4;                 // MFMA k-chunk
    const int l15 = lane & 15;
    const int cs = (q - (l15 >> 1)) & 3;     // swizzled slot holding chunk q
    const int rofs = l15 * 32 + cs * 8;      // f16 units within a 16-row chunk
    f16x8 av[4], wv0[4], wv1[4];
#pragma unroll
    for (int i = 0; i < 4; ++i)
      av[i] = *(const f16x8*)&As[(wm * 4 + i) * 512 + rofs];
#pragma unroll
    for (int i = 0; i < 4; ++i) {
      wv0[i] = *(const f16x8*)&Ws[0][(wn * 4 + i) * 512 + rofs];
      wv1[i] = *(const f16x8*)&Ws[1][(wn * 4 + i) * 512 + rofs];
    }
#pragma unroll
    for (int i = 0; i < 4; ++i)
#pragma unroll
      for (int j = 0; j < 4; ++j) {
        acc[i][j]     = __builtin_amdgcn_mfma_f32_16x16x32_f16(av[i], wv0[j], acc[i][j], 0, 0, 0);
        acc[i][4 + j] = __builtin_amdgcn_mfma_f32_16x16x32_f16(av[i], wv1[j], acc[i][4 + j], 0, 0, 0);
      }
  }

  const int r0 = (lane >> 4) * 4, cn = lane & 15;
  const size_t obase = (size_t)(dir * 64 + b) * CT;
#pragma unroll
  for (int i = 0; i < 4; ++i) {
    const int m = wm * 64 + i * 16 + r0;
#pragma unroll
    for (int j = 0; j < 4; ++j) {
      const int n = n0 + wn * 64 + j * 16 + cn;
#pragma unroll
      for (int r = 0; r < 4; ++r) {
        gxc[(obase + m + r) * 1280 + n]       = (f16)acc[i][j][r];
        gxc[(obase + m + r) * 1280 + n + 128] = (f16)acc[i][4 + j][r];
      }
    }
  }
}

// ------------------------- LSTM scan (one chunk) ---------------------------
// R19: 128 WGs x 1024 threads, one per (b,dir). int8 Whh register-resident:
// 100 u32/thread, occupancy PINNED to exactly 4 waves/EU so the allocator
// gets the full 128-VGPR budget (R17's launch_bounds(1024,4) was only a
// minimum -> allocator chose 8 waves/EU = 64 VGPRs = spill).
__global__ void __launch_bounds__(1024)
__attribute__((amdgpu_waves_per_eu(4, 4)))
lstm_scan_chunk(const uint32_t* __restrict__ wqbuf,  // int8 weights
                const float* __restrict__ scales,    // [6][1280] s_r
                const f16* __restrict__ gxc,         // [2*64*CT][1280]
                const float* __restrict__ bias,      // [2][1280] this layer
                const int* __restrict__ lens,
                f16* __restrict__ xnext,             // [65536][640]
                f16* __restrict__ hsave,             // [128][320]
                float* __restrict__ csave,           // [128][320]
                int layer, int c0) {
  const int wg = blockIdx.x;          // 0..127
  const int b = wg >> 1, dir = wg & 1;
  const int tid = threadIdx.x;        // 0..1023
  const int kq = tid & 3, qi = tid >> 2;   // qi in [0,256)
  const int slot = layer * 2 + dir;

  __shared__ __align__(16) uint32_t hqw[80];      // h int8-packed (320 B)
  __shared__ int ylds[1280];                      // exact int32 dot sums
  __shared__ float bsl[1280];                     // bias (this layer/dir)
  __shared__ float ssl[1280];                     // scale/127 per row
  __shared__ __align__(16) f16 hstage[64 * 320];  // 40 KB ring

  // weights: rows i*256+qi (i=0..4), cols kq*80 + j*4.. (j=0..19)
  uint32_t w[5][20];
  {
    const uint32_t* wb = wqbuf + (size_t)slot * 5 * 20 * 1024;
#pragma unroll
    for (int i = 0; i < 5; ++i)
#pragma unroll
      for (int j = 0; j < 20; ++j)
        w[i][j] = wb[(i * 20 + j) * 1024 + tid];
  }

  for (int v = tid; v < 1280; v += 1024) {
    bsl[v] = bias[dir * 1280 + v];
    ssl[v] = scales[slot * 1280 + v] * (1.f / 127.f);
  }

  const int len = lens[b];
  float c_state = 0.f;
  if (tid < 320) {
    float hv0 = (c0 == 0) ? 0.f : (float)hsave[wg * 320 + tid];
    ((uint8_t*)hqw)[tid] = (uint8_t)(int8_t)(int)rintf(hv0 * 127.f);
    if (c0 > 0) c_state = csave[wg * 320 + tid];
  }
  __syncthreads();

  const size_t grow0 = (size_t)(dir * 64 + b) * CT;

  float gxi = 0.f, gxf = 0.f, gxg = 0.f, gxo = 0.f;
  if (tid < 320) {
    const f16* gp = gxc + grow0 * 1280 + tid;
    gxi = (float)gp[0]; gxf = (float)gp[320]; gxg = (float)gp[640]; gxo = (float)gp[960];
  }

  for (int tl = 0; tl < CT; ++tl) {
    float nxi = 0.f, nxf = 0.f, nxg = 0.f, nxo = 0.f;
    if (tid < 320 && tl + 1 < CT) {
      const f16* gp = gxc + (grow0 + tl + 1) * 1280 + tid;
      nxi = (float)gp[0]; nxf = (float)gp[320]; nxg = (float)gp[640]; nxo = (float)gp[960];
    }

    // ---- y = Whh . h in int8: 100 v_dot4 per thread, broadcast LDS reads --
    int acc0 = 0, acc1 = 0, acc2 = 0, acc3 = 0, acc4 = 0;
    {
      const u32x4* hv4 = (const u32x4*)&hqw[kq * 20];
#pragma unroll
      for (int jb = 0; jb < 5; ++jb) {
        u32x4 hv = hv4[jb];
#pragma unroll
        for (int e = 0; e < 4; ++e) {
          const int j = jb * 4 + e;
          const int hword = (int)hv[e];
          acc0 = dot4i8((int)w[0][j], hword, acc0);
          acc1 = dot4i8((int)w[1][j], hword, acc1);
          acc2 = dot4i8((int)w[2][j], hword, acc2);
          acc3 = dot4i8((int)w[3][j], hword, acc3);
          acc4 = dot4i8((int)w[4][j], hword, acc4);
        }
      }
    }
    {
      int av[5] = {acc0, acc1, acc2, acc3, acc4};
#pragma unroll
      for (int i = 0; i < 5; ++i) {
        int v = av[i];
        v += __shfl_xor(v, 1, 64);
        v += __shfl_xor(v, 2, 64);
        if (kq == 0) ylds[i * 256 + qi] = v;
      }
    }

    if ((tl & 31) == 0 && tl > 0) {
      const int tw = tl - 32;
#pragma unroll
      for (int it = 0; it < 2; ++it) {
        const int slt = it * 1024 + tid;
        if (slt < 1280) {
          const int r = (int)(((unsigned)slt * 1639u) >> 16);   // slt/40
          const int j = slt - r * 40;
          const int sp = c0 * CT + tw + r;
          const int ttp = dir ? ((sp < len) ? (len - 1 - sp) : sp) : sp;
          f16x8 v = *(const f16x8*)&hstage[((tw + r) & 63) * 320 + j * 8];
          *(f16x8*)&xnext[(size_t)(b * 1024 + ttp) * 640 + dir * 320 + j * 8] = v;
        }
      }
    }
    __syncthreads();                              // B1: ylds ready

    if (tid < 320) {
      const int u = tid;
      float pi = ssl[u]       * (float)ylds[u]       + gxi + bsl[u];
      float pf = ssl[u + 320] * (float)ylds[u + 320] + gxf + bsl[u + 320];
      float pg = ssl[u + 640] * (float)ylds[u + 640] + gxg + bsl[u + 640];
      float po = ssl[u + 960] * (float)ylds[u + 960] + gxo + bsl[u + 960];
      float ig = fsigm(pi);
      float fg = fsigm(pf);
      float gg = ftanh(pg);
      float og = fsigm(po);
      c_state = fg * c_state + ig * gg;
      float hv = og * ftanh(c_state);
      hstage[(tl & 63) * 320 + u] = (f16)hv;
      ((uint8_t*)hqw)[u] = (uint8_t)(int8_t)(int)rintf(hv * 127.f);
    }
    __syncthreads();                              // B2: hqw ready for next dot

    gxi = nxi; gxf = nxf; gxg = nxg; gxo = nxo;
  }

  {
    const int tw = CT - 32;
#pragma unroll
    for (int it = 0; it < 2; ++it) {
      const int slt = it * 1024 + tid;
      if (slt < 1280) {
        const int r = (int)(((unsigned)slt * 1639u) >> 16);
        const int j = slt - r * 40;
        const int sp = c0 * CT + tw + r;
        const int ttp = dir ? ((sp < len) ? (len - 1 - sp) : sp) : sp;
        f16x8 v = *(const f16x8*)&hstage[((tw + r) & 63) * 320 + j * 8];
        *(f16x8*)&xnext[(size_t)(b * 1024 + ttp) * 640 + dir * 320 + j * 8] = v;
      }
    }
  }
  if (tid < 320) {
    hsave[wg * 320 + tid] = hstage[63 * 320 + tid];
    csave[wg * 320 + tid] = c_state;
  }
}

// ---------------------- projection GEMM (f32 out) --------------------------
__global__ __launch_bounds__(256)
void gemm_proj(const f16* __restrict__ A, const f16* __restrict__ W,
               float* __restrict__ outf, int lda, int kTiles, int ldo) {
  __shared__ __align__(16) f16 As[128 * 32];
  __shared__ __align__(16) f16 Ws[128 * 32];
  const int tid = threadIdx.x;
  const int lane = tid & 63, wid = tid >> 6;
  const int wm = wid >> 1, wn = wid & 1;
  const int m0 = blockIdx.y * 128, n0 = blockIdx.x * 128;
  const int r_base = lane >> 2;
  const int chs = ((((lane & 3) + (r_base >> 1)) & 3)) * 8;  // swizzled SRC chunk

  f32x4 acc[4][4] = {};

  for (int kt = 0; kt < kTiles; ++kt) {
    const int k0 = kt * 32;
    __syncthreads();
#pragma unroll
    for (int hh = 0; hh < 2; ++hh) {
      const int c = wid * 2 + hh;
      stage16(&As[c * 512], A + (size_t)(m0 + c * 16 + r_base) * lda + k0 + chs);
      stage16(&Ws[c * 512], W + (size_t)(n0 + c * 16 + r_base) * lda + k0 + chs);
    }
    __syncthreads();

    const int q = lane >> 4;
    const int l15 = lane & 15;
    const int cs = (q - (l15 >> 1)) & 3;
    const int rofs = l15 * 32 + cs * 8;
    f16x8 av[4], wv[4];
#pragma unroll
    for (int i = 0; i < 4; ++i)
      av[i] = *(const f16x8*)&As[(wm * 4 + i) * 512 + rofs];
#pragma unroll
    for (int i = 0; i < 4; ++i)
      wv[i] = *(const f16x8*)&Ws[(wn * 4 + i) * 512 + rofs];
#pragma unroll
    for (int i = 0; i < 4; ++i)
#pragma unroll
      for (int j = 0; j < 4; ++j)
        acc[i][j] = __builtin_amdgcn_mfma_f32_16x16x32_f16(av[i], wv[j], acc[i][j], 0, 0, 0);
  }

  const int r0 = (lane >> 4) * 4, cn = lane & 15;
#pragma unroll
  for (int i = 0; i < 4; ++i) {
    const int m = m0 + wm * 64 + i * 16 + r0;
#pragma unroll
    for (int j = 0; j < 4; ++j) {
      const int n = n0 + wn * 64 + j * 16 + cn;
#pragma unroll
      for (int r = 0; r < 4; ++r)
        outf[(size_t)(m + r) * ldo + n] = acc[i][j][r];
    }
  }
}

// ------------------------- logsumexp over K=72 ------------------------------
__global__ void lse_kernel(const float* __restrict__ Z, const float* __restrict__ b_lin,
                           float* __restrict__ lseout) {
  int row = blockIdx.x * 4 + (threadIdx.x >> 6);
  int l = threadIdx.x & 63;
  const float* z = Z + (size_t)row * 128;
  float v0 = (l < 72) ? z[l] + b_lin[l] : NEGF;
  float v1 = (l < 8) ? z[l + 64] + b_lin[l + 64] : NEGF;
  float m = fmaxf(v0, v1);
#pragma unroll
  for (int o = 32; o; o >>= 1) m = fmaxf(m, __shfl_xor(m, o, 64));
  float s = ((l < 72) ? __expf(v0 - m) : 0.f) + ((l < 8) ? __expf(v1 - m) : 0.f);
#pragma unroll
  for (int o = 32; o; o >>= 1) s += __shfl_xor(s, o, 64);
  if (l == 0) lseout[row] = m + __logf(s);
}

// --------------- emission pre-gather: emc[b][t][s] (f16) -------------------
// emc = (Z[t][ext[s]] + b_lin[ext[s]] - lse[t]) * log2(e).  Base-2 domain so
// the ctc recursion uses raw v_exp_f32 / v_log_f32.
__global__ void emz_kernel(const float* __restrict__ Z, const float* __restrict__ lse,
                           const float* __restrict__ b_lin,
                           const int* __restrict__ labels,
                           f16* __restrict__ emc) {
  const int b = blockIdx.y;
  const int t0 = blockIdx.x * 4;
  const int tid = threadIdx.x;   // 256
  __shared__ int ext[200];
  __shared__ float bls[200];
  if (tid < 200) {
    int e = (tid < 193 && (tid & 1)) ? labels[b * 96 + (tid >> 1)] : 0;
    ext[tid] = e;
    bls[tid] = b_lin[e];
  }
  __syncthreads();
#pragma unroll
  for (int dt = 0; dt < 4; ++dt) {
    const int t = t0 + dt;
    const float lst = lse[b * 1024 + t];
    const float* zr = Z + ((size_t)(b * 1024 + t)) * 128;
    for (int s = tid; s < 200; s += 256)
      emc[((size_t)(b * 1024 + t)) * 200 + s] =
          (f16)((zr[ext[s]] + bls[s] - lst) * 1.4426950408889634f);
  }
}

// ------------------------------ CTC forward ---------------------------------
__global__ void ctc_kernel(const f16* __restrict__ emc,
                           const int* __restrict__ labels, const int* __restrict__ inlen,
                           const int* __restrict__ lablen, float* __restrict__ num) {
  const int b = blockIdx.x;
  const int lane = threadIdx.x;          // 64
  __shared__ int ext[200];
  __shared__ float afin[200];

  for (int s = lane; s < 200; s += 64)
    ext[s] = (s < 193 && (s & 1)) ? labels[b * 96 + (s >> 1)] : 0;
  __syncthreads();

  const int L = lablen[b], len = inlen[b];
  const int Send = 2 * L + 1;
  const f16* eb = emc + (size_t)b * 1024 * 200;

  float a[4];
  bool  skp[4], val[4];
#pragma unroll
  for (int j = 0; j < 4; ++j) {
    const int s = lane * 4 + j;
    val[j] = (s < Send) && (s < 193);
    skp[j] = (s < 193) && (s & 1) && (s >= 2) && (ext[s] != ext[s - 2]);
  }
  {
    f16x4v e0 = *(const f16x4v*)&eb[lane * 4];   // t = 0
#pragma unroll
    for (int j = 0; j < 4; ++j) {
      const int s = lane * 4 + j;
      a[j] = (s <= 1 && val[j]) ? (float)e0[j] : NEGF;
    }
  }

  auto step = [&](f16x4v ev) {
    float p3 = __shfl_up(a[3], 1, 64);
    float p2 = __shfl_up(a[2], 1, 64);
    if (lane == 0) { p3 = NEGF; p2 = NEGF; }
    const float x2[4] = {p3, a[0], a[1], a[2]};
    const float x3[4] = {p2, p3, a[0], a[1]};
#pragma unroll
    for (int j = 0; j < 4; ++j) {
      const float xa = a[j], xb = x2[j];
      const float xc = skp[j] ? x3[j] : NEGF;
      const float m = fmaxf(xa, fmaxf(xb, xc));
      const float sum = fexp2(xa - m) + fexp2(xb - m) + fexp2(xc - m);
      const float nv = m + flog2(sum) + (float)ev[j];
      a[j] = val[j] ? nv : NEGF;
    }
  };

  // depth-8 register ring, fully static slot indexing
  f16x4v ring[8];
#pragma unroll
  for (int d = 1; d <= 8; ++d) {
    const int r = (d < len) ? d : (len - 1);
    ring[d & 7] = *(const f16x4v*)&eb[(size_t)r * 200 + lane * 4];
  }

  int t = 1;
  for (; t + 8 <= len; t += 8) {
#pragma unroll
    for (int k = 0; k < 8; ++k) {
      const int slot = (1 + k) & 7;        // t == 1 (mod 8)
      f16x4v ev = ring[slot];
      const int tp = t + k + 8;
      if (tp < len)
        ring[slot] = *(const f16x4v*)&eb[(size_t)tp * 200 + lane * 4];
      step(ev);
    }
  }
  for (; t < len; ++t)
    step(*(const f16x4v*)&eb[(size_t)t * 200 + lane * 4]);

#pragma unroll
  for (int j = 0; j < 4; ++j) {
    const int s = lane * 4 + j;
    if (s < 193) afin[s] = a[j];
  }
  __syncthreads();
  if (lane == 0) {
    const float aL = afin[2 * L], aLm1 = afin[2 * L - 1];
    const float m = fmaxf(aL, aLm1);
    // back to natural log for the final reduction
    num[b] = 0.6931471805599453f * (m + flog2(fexp2(aL - m) + fexp2(aLm1 - m)));
  }
}

__global__ void final_kernel(const float* __restrict__ num, float* __restrict__ out) {
  int l = threadIdx.x;  // 64
  float v = -1.1f * num[l];
#pragma unroll
  for (int o = 32; o; o >>= 1) v += __shfl_xor(v, o, 64);
  if (l == 0) out[0] = v * (1.f / 64.f);
}

__global__ void sentinel_kernel(float* __restrict__ out, float code) { out[0] = code; }

// ------------------------------ launcher ------------------------------------
extern "C" void kernel_launch(void* const* d_in, const int* in_sizes, int n_in,
                              void* d_out, int out_size, void* d_ws, size_t ws_size,
                              hipStream_t stream) {
  (void)in_sizes; (void)n_in; (void)out_size;

  const float* logits   = (const float*)d_in[0];
  const int*   labels   = (const int*)d_in[1];
  const int*   in_lens  = (const int*)d_in[2];
  const int*   lab_lens = (const int*)d_in[3];
  const float* Wih0     = (const float*)d_in[4];
  const float* Whh0     = (const float*)d_in[5];
  const float* b0       = (const float*)d_in[6];
  const float* Wih      = (const float*)d_in[7];
  const float* Whh      = (const float*)d_in[8];
  const float* bb       = (const float*)d_in[9];
  const float* W_lin    = (const float*)d_in[10];
  const float* b_lin    = (const float*)d_in[11];

  const size_t NEED = (size_t)224 * 1024 * 1024;
  if (ws_size < NEED) {
    sentinel_kernel<<<1, 1, 0, stream>>>((float*)d_out, -(float)(ws_size >> 20));
    return;
  }

  char* ws = (char*)d_ws;
  size_t off = 0;
  auto alloc = [&](size_t bytes) -> char* {
    char* p = ws + off;
    off += (bytes + 255) & ~(size_t)255;
    return p;
  };
  f16*      Xa     = (f16*)alloc((size_t)65536 * 640 * 2);        // 83.9 MB
  f16*      Xb     = (f16*)alloc((size_t)65536 * 640 * 2);        // 83.9 MB
  f16*      gxc    = (f16*)alloc((size_t)2 * 64 * CT * 1280 * 2); // 41.9 MB
  f16*      Wt0    = (f16*)alloc((size_t)2560 * 128 * 2);
  f16*      Wt12   = (f16*)alloc((size_t)2 * 2560 * 640 * 2);
  f16*      WtL    = (f16*)alloc((size_t)128 * 640 * 2);
  uint32_t* wqi    = (uint32_t*)alloc((size_t)6 * 5 * 20 * 1024 * 4);  // 2.46 MB
  float*    scales = (float*)alloc((size_t)6 * 1280 * 4);
  float*    lseb   = (float*)alloc((size_t)65536 * 4);
  float*    num    = (float*)alloc(64 * 4);
  f16*      hsave  = (f16*)alloc((size_t)128 * 320 * 2);
  float*    csave  = (float*)alloc((size_t)128 * 320 * 4);
  // aliases (disjoint lifetimes)
  f16*      A0     = Xb;           // dead after layer 0; Xb first written layer 1
  float*    Z      = (float*)gxc;  // gxc dead after layer-2 scan
  f16*      emc    = Xa;           // Xa dead after gemm_proj

  conv_logits<<<32768, 256, 0, stream>>>(logits, A0);
  conv_wt0<<<1280, 256, 0, stream>>>(Wih0, Wt0);
  conv_copy<<<12800, 256, 0, stream>>>(Wih, Wt12, 3276800);
  conv_wtl<<<320, 256, 0, stream>>>(W_lin, WtL);
  conv_scale<<<1920, 256, 0, stream>>>(Whh0, Whh, scales);
  conv_wq<<<2400, 256, 0, stream>>>(Whh0, Whh, scales, wqi);

  // layer 0: A0 -> Xa
  for (int c = 0; c < 1024 / CT; ++c) {
    gemm_chunk<<<dim3(5, 128), 256, 0, stream>>>(A0, Wt0, gxc, in_lens, 128, 4, c);
    lstm_scan_chunk<<<128, 1024, 0, stream>>>(wqi, scales, gxc, b0, in_lens, Xa,
                                              hsave, csave, 0, c);
  }
  // layer 1: Xa -> Xb
  for (int c = 0; c < 1024 / CT; ++c) {
    gemm_chunk<<<dim3(5, 128), 256, 0, stream>>>(Xa, Wt12, gxc, in_lens, 640, 20, c);
    lstm_scan_chunk<<<128, 1024, 0, stream>>>(wqi, scales, gxc, bb, in_lens, Xb,
                                              hsave, csave, 1, c);
  }
  // layer 2: Xb -> Xa
  for (int c = 0; c < 1024 / CT; ++c) {
    gemm_chunk<<<dim3(5, 128), 256, 0, stream>>>(Xb, Wt12 + (size_t)2560 * 640, gxc,
                                                 in_lens, 640, 20, c);
    lstm_scan_chunk<<<128, 1024, 0, stream>>>(wqi, scales, gxc, bb + 2560, in_lens, Xa,
                                              hsave, csave, 2, c);
  }
  // projection: Xa -> Z (f32)
  gemm_proj<<<dim3(1, 512), 256, 0, stream>>>(Xa, WtL, Z, 640, 20, 128);

  lse_kernel<<<16384, 256, 0, stream>>>(Z, b_lin, lseb);
  emz_kernel<<<dim3(256, 64), 256, 0, stream>>>(Z, lseb, b_lin, labels, emc);
  ctc_kernel<<<64, 64, 0, stream>>>(emc, labels, in_lens, lab_lens, num);
  final_kernel<<<1, 64, 0, stream>>>(num, (float*)d_out);
}

// Round 12
// 8416.736 us; speedup vs baseline: 1.3246x; 1.3246x over previous
//
#include <hip/hip_runtime.h>
#include <cstdint>
#include <cstddef>

// ---------------------------------------------------------------------------
// CTC-CRF BLSTM pipeline for MI355X.  B=64 T=1024 IDIM=120 HDIM=320 K=72
// den == 0 analytically; batch sort is a no-op under the batch mean. Skipped.
//
// R20 deltas vs R19 (11.1 ms; 1024-thr VGPR=64 again):
//  - Allocator model closed: it targets 2 WGs/CU whenever LDS allows
//    (57KB x 2 <= 160KB), then budgets VGPRs = 512/(waves per SIMD):
//    512-thr -> 128, 1024-thr -> 64. Every attribute we tried is
//    overridden by this occupancy-derived cap -- but LDS is not.
//  - Fix: revert to R18 (best, 8.51 ms, scan 289us, passed) and pad
//    hstage 64x320 -> 112x320 f16: scan LDS ~87KB > 80KB -> only 1 WG/CU
//    -> 8 waves/CU = 2 waves/SIMD -> 256-VGPR budget. Kernel needs ~230
//    (200 weight dwords + ~30 working) -> ZERO spill for the first time.
//    Ring indexing (&63) and all math bit-identical to R18.
//  - Verification bit: VGPR_Count must read ~230-256 (not 128).
// ---------------------------------------------------------------------------

typedef _Float16 f16;
typedef _Float16 h2v   __attribute__((ext_vector_type(2)));
typedef _Float16 f16x4v __attribute__((ext_vector_type(4)));
typedef _Float16 f16x8 __attribute__((ext_vector_type(8)));
typedef float    f32x4 __attribute__((ext_vector_type(4)));
typedef uint32_t u32x4 __attribute__((ext_vector_type(4)));

#define NEGF (-1e30f)
#define CT 128

__device__ __forceinline__ int dot4i8(int a, int b, int c) {
#if __has_builtin(__builtin_amdgcn_sdot4)
  return __builtin_amdgcn_sdot4(a, b, c, false);
#else
  int s = c;
#pragma unroll
  for (int e = 0; e < 4; ++e)
    s += (int)(int8_t)(a >> (8 * e)) * (int)(int8_t)(b >> (8 * e));
  return s;
#endif
}

__device__ __forceinline__ float fast_rcp(float x) {
#if __has_builtin(__builtin_amdgcn_rcpf)
  return __builtin_amdgcn_rcpf(x);
#else
  return 1.f / x;
#endif
}
__device__ __forceinline__ float fsigm(float x) { return fast_rcp(1.f + __expf(-x)); }
__device__ __forceinline__ float ftanh(float x) { return 1.f - 2.f * fast_rcp(1.f + __expf(2.f * x)); }

__device__ __forceinline__ float fexp2(float x) {
#if __has_builtin(__builtin_amdgcn_exp2f)
  return __builtin_amdgcn_exp2f(x);
#else
  return exp2f(x);
#endif
}
__device__ __forceinline__ float flog2(float x) {
#if __has_builtin(__builtin_amdgcn_logf)
  return __builtin_amdgcn_logf(x);
#else
  return log2f(x);
#endif
}

__device__ __forceinline__ void stage16(f16* lds, const f16* g) {
#if __has_builtin(__builtin_amdgcn_global_load_lds)
  __builtin_amdgcn_global_load_lds(
      (const __attribute__((address_space(1))) uint32_t*)g,
      (__attribute__((address_space(3))) uint32_t*)lds, 16, 0, 0);
#else
  int lane = threadIdx.x & 63;
  *(f16x8*)&lds[lane * 8] = *(const f16x8*)g;
#endif
}

// ---------------------------- convert kernels ------------------------------

__global__ void conv_logits(const float* __restrict__ src, f16* __restrict__ dst) {
  int idx = blockIdx.x * 256 + threadIdx.x;      // < 65536*128
  int row = idx >> 7, k = idx & 127;
  dst[idx] = (f16)((k < 120) ? src[(size_t)row * 120 + k] : 0.f);
}

__global__ void conv_wt0(const float* __restrict__ w, f16* __restrict__ dst) {
  int idx = blockIdx.x * 256 + threadIdx.x;      // < 2560*128
  int n = idx >> 7, k = idx & 127;
  dst[idx] = (f16)((k < 120) ? w[(size_t)n * 120 + k] : 0.f);
}

__global__ void conv_copy(const float* __restrict__ src, f16* __restrict__ dst, int count) {
  int idx = blockIdx.x * 256 + threadIdx.x;
  if (idx < count) dst[idx] = (f16)src[idx];
}

__global__ void conv_wtl(const float* __restrict__ w, f16* __restrict__ dst) {
  int idx = blockIdx.x * 256 + threadIdx.x;      // < 128*640
  int n = idx / 640, k = idx % 640;
  dst[idx] = (f16)((n < 72) ? w[(size_t)n * 640 + k] : 0.f);
}

// per-row abs-max scales for Whh int8 quantization: s_r = rowmax/127.
// rows indexed (slot*1280 + r), slot = layer*2 + dir (6 slots).
__global__ void conv_scale(const float* __restrict__ whh0, const float* __restrict__ whh,
                           float* __restrict__ scales) {
  int row = blockIdx.x * 4 + (threadIdx.x >> 6);   // < 7680
  int lane = threadIdx.x & 63;
  int slot = row / 1280, r = row - slot * 1280;
  const float* src = (slot < 2) ? (whh0 + ((size_t)slot * 1280 + r) * 320)
                                : (whh  + ((size_t)(slot - 2) * 1280 + r) * 320);
  float m = 0.f;
  for (int k = lane; k < 320; k += 64) m = fmaxf(m, fabsf(src[k]));
#pragma unroll
  for (int o = 32; o; o >>= 1) m = fmaxf(m, __shfl_xor(m, o, 64));
  if (lane == 0) scales[row] = fmaxf(m, 1e-20f) * (1.f / 127.f);
}

// Whh -> int8 packed scan layout (512-thread WGs, R16/R18-proven): word for
// (slot, i, j, t) holds row r = i*128 + (t>>2), cols k0..k0+3 with
// k0 = (t&3)*80 + j*4.
__global__ void conv_wq(const float* __restrict__ whh0, const float* __restrict__ whh,
                        const float* __restrict__ scales, uint32_t* __restrict__ dst) {
  int o = blockIdx.x * 256 + threadIdx.x;          // < 6*10*20*512 = 614400
  int t = o & 511;
  int g = o >> 9;
  int j = g % 20;
  int g2 = g / 20;
  int i = g2 % 10;
  int slot = g2 / 10;
  int qi = t >> 2, kq = t & 3;
  int r = i * 128 + qi;
  int k0 = kq * 80 + j * 4;
  const float* src = (slot < 2) ? (whh0 + ((size_t)slot * 1280 + r) * 320)
                                : (whh  + ((size_t)(slot - 2) * 1280 + r) * 320);
  float s = scales[slot * 1280 + r];
  float rs = fast_rcp(s);
  uint32_t w = 0;
#pragma unroll
  for (int e = 0; e < 4; ++e) {
    float q = rintf(src[k0 + e] * rs);
    q = fminf(fmaxf(q, -127.f), 127.f);
    w |= ((uint32_t)(uint8_t)(int8_t)(int)q) << (8 * e);
  }
  dst[o] = w;
}

// --------------------- gather-GEMM for one time chunk ----------------------
__global__ __launch_bounds__(256)
void gemm_chunk(const f16* __restrict__ A, const f16* __restrict__ W,
                f16* __restrict__ gxc, const int* __restrict__ lens,
                int lda, int kTiles, int c0) {
  __shared__ __align__(16) f16 As[128 * 32];
  __shared__ __align__(16) f16 Ws[2][128 * 32];
  const int tid = threadIdx.x;
  const int lane = tid & 63, wid = tid >> 6;
  const int wm = wid >> 1, wn = wid & 1;
  const int dir = blockIdx.y >> 6, b = blockIdx.y & 63;
  const int n0 = blockIdx.x * 256;
  const int r_base = lane >> 2;                              // 0..15
  const int chs = ((((lane & 3) + (r_base >> 1)) & 3)) * 8;  // swizzled SRC k-chunk
  const int len = lens[b];

  f32x4 acc[4][8] = {};

  for (int kt = 0; kt < kTiles; ++kt) {
    const int k0 = kt * 32;
    __syncthreads();
#pragma unroll
    for (int hh = 0; hh < 2; ++hh) {
      const int c = wid * 2 + hh;
      const int j = c * 16 + r_base;                     // step within chunk
      const int s = c0 * CT + j;
      const int tt = dir ? ((s < len) ? (len - 1 - s) : s) : s;
      stage16(&As[c * 512], A + (size_t)(b * 1024 + tt) * lda + k0 + chs);
    }
#pragma unroll
    for (int hh = 0; hh < 4; ++hh) {
      const int c = wid * 4 + hh;                        // 0..15
      const int tile = c >> 3, cc = c & 7;
      stage16(&Ws[tile][cc * 512],
              W + (size_t)(dir * 1280 + n0 + tile * 128 + cc * 16 + r_base) * lda + k0 + chs);
    }
    __syncthreads();

    const int q = lane >> 4;                 // MFMA k-chunk
    const int l15 = lane & 15;
    const int cs = (q - (l15 >> 1)) & 3;     // swizzled slot holding chunk q
    const int rofs = l15 * 32 + cs * 8;      // f16 units within a 16-row chunk
    f16x8 av[4], wv0[4], wv1[4];
#pragma unroll
    for (int i = 0; i < 4; ++i)
      av[i] = *(const f16x8*)&As[(wm * 4 + i) * 512 + rofs];
#pragma unroll
    for (int i = 0; i < 4; ++i) {
      wv0[i] = *(const f16x8*)&Ws[0][(wn * 4 + i) * 512 + rofs];
      wv1[i] = *(const f16x8*)&Ws[1][(wn * 4 + i) * 512 + rofs];
    }
#pragma unroll
    for (int i = 0; i < 4; ++i)
#pragma unroll
      for (int j = 0; j < 4; ++j) {
        acc[i][j]     = __builtin_amdgcn_mfma_f32_16x16x32_f16(av[i], wv0[j], acc[i][j], 0, 0, 0);
        acc[i][4 + j] = __builtin_amdgcn_mfma_f32_16x16x32_f16(av[i], wv1[j], acc[i][4 + j], 0, 0, 0);
      }
  }

  const int r0 = (lane >> 4) * 4, cn = lane & 15;
  const size_t obase = (size_t)(dir * 64 + b) * CT;
#pragma unroll
  for (int i = 0; i < 4; ++i) {
    const int m = wm * 64 + i * 16 + r0;
#pragma unroll
    for (int j = 0; j < 4; ++j) {
      const int n = n0 + wn * 64 + j * 16 + cn;
#pragma unroll
      for (int r = 0; r < 4; ++r) {
        gxc[(obase + m + r) * 1280 + n]       = (f16)acc[i][j][r];
        gxc[(obase + m + r) * 1280 + n + 128] = (f16)acc[i][4 + j][r];
      }
    }
  }
}

// ------------------------- LSTM scan (one chunk) ---------------------------
// R20: 128 WGs x 512 threads, one per (b,dir). int8 Whh register-resident
// (200 u32/thread). hstage padded so LDS ~87KB > 80KB -> 1 WG/CU -> the
// allocator's occupancy-derived VGPR budget becomes 256 -> no spill.
__global__ void __launch_bounds__(512)
__attribute__((amdgpu_waves_per_eu(2, 2)))
lstm_scan_chunk(const uint32_t* __restrict__ wqbuf,  // int8 weights
                const float* __restrict__ scales,    // [6][1280] s_r
                const f16* __restrict__ gxc,         // [2*64*CT][1280]
                const float* __restrict__ bias,      // [2][1280] this layer
                const int* __restrict__ lens,
                f16* __restrict__ xnext,             // [65536][640]
                f16* __restrict__ hsave,             // [128][320]
                float* __restrict__ csave,           // [128][320]
                int layer, int c0) {
  const int wg = blockIdx.x;          // 0..127
  const int b = wg >> 1, dir = wg & 1;
  const int tid = threadIdx.x;        // 0..511
  const int kq = tid & 3, qi = tid >> 2;   // qi in [0,128)
  const int slot = layer * 2 + dir;

  __shared__ __align__(16) uint32_t hqw[80];       // h int8-packed (320 B)
  __shared__ int ylds[1280];                       // exact int32 dot sums
  __shared__ float bsl[1280];                      // bias (this layer/dir)
  __shared__ float ssl[1280];                      // scale/127 per row
  // Ring uses rows [0,64); rows [64,112) are OCCUPANCY PADDING: they push
  // LDS to ~87KB so only 1 WG/CU fits -> 2 waves/SIMD -> 256-VGPR budget.
  __shared__ __align__(16) f16 hstage[112 * 320];

  // weights: rows i*128+qi (i=0..9), cols kq*80 + j*4.. (j=0..19)
  uint32_t w[10][20];
  {
    const uint32_t* wb = wqbuf + (size_t)slot * 10 * 20 * 512;
#pragma unroll
    for (int i = 0; i < 10; ++i)
#pragma unroll
      for (int j = 0; j < 20; ++j)
        w[i][j] = wb[(i * 20 + j) * 512 + tid];
  }

  for (int v = tid; v < 1280; v += 512) {
    bsl[v] = bias[dir * 1280 + v];
    ssl[v] = scales[slot * 1280 + v] * (1.f / 127.f);
  }

  const int len = lens[b];
  float c_state = 0.f;
  if (tid < 320) {
    float hv0 = (c0 == 0) ? 0.f : (float)hsave[wg * 320 + tid];
    ((uint8_t*)hqw)[tid] = (uint8_t)(int8_t)(int)rintf(hv0 * 127.f);
    if (c0 > 0) c_state = csave[wg * 320 + tid];
  }
  __syncthreads();

  const size_t grow0 = (size_t)(dir * 64 + b) * CT;

  float gxi = 0.f, gxf = 0.f, gxg = 0.f, gxo = 0.f;
  if (tid < 320) {
    const f16* gp = gxc + grow0 * 1280 + tid;
    gxi = (float)gp[0]; gxf = (float)gp[320]; gxg = (float)gp[640]; gxo = (float)gp[960];
  }

  for (int tl = 0; tl < CT; ++tl) {
    float nxi = 0.f, nxf = 0.f, nxg = 0.f, nxo = 0.f;
    if (tid < 320 && tl + 1 < CT) {
      const f16* gp = gxc + (grow0 + tl + 1) * 1280 + tid;
      nxi = (float)gp[0]; nxf = (float)gp[320]; nxg = (float)gp[640]; nxo = (float)gp[960];
    }

    // ---- y = Whh . h in int8: 200 v_dot4 per thread, broadcast LDS reads --
    int acc0 = 0, acc1 = 0, acc2 = 0, acc3 = 0, acc4 = 0;
    int acc5 = 0, acc6 = 0, acc7 = 0, acc8 = 0, acc9 = 0;
    {
      const u32x4* hv4 = (const u32x4*)&hqw[kq * 20];
#pragma unroll
      for (int jb = 0; jb < 5; ++jb) {
        u32x4 hv = hv4[jb];
#pragma unroll
        for (int e = 0; e < 4; ++e) {
          const int j = jb * 4 + e;
          const int hword = (int)hv[e];
          acc0 = dot4i8((int)w[0][j], hword, acc0);
          acc1 = dot4i8((int)w[1][j], hword, acc1);
          acc2 = dot4i8((int)w[2][j], hword, acc2);
          acc3 = dot4i8((int)w[3][j], hword, acc3);
          acc4 = dot4i8((int)w[4][j], hword, acc4);
          acc5 = dot4i8((int)w[5][j], hword, acc5);
          acc6 = dot4i8((int)w[6][j], hword, acc6);
          acc7 = dot4i8((int)w[7][j], hword, acc7);
          acc8 = dot4i8((int)w[8][j], hword, acc8);
          acc9 = dot4i8((int)w[9][j], hword, acc9);
        }
      }
    }
    {
      int av[10] = {acc0, acc1, acc2, acc3, acc4, acc5, acc6, acc7, acc8, acc9};
#pragma unroll
      for (int i = 0; i < 10; ++i) {
        int v = av[i];
        v += __shfl_xor(v, 1, 64);
        v += __shfl_xor(v, 2, 64);
        if (kq == 0) ylds[i * 128 + qi] = v;
      }
    }

    if ((tl & 31) == 0 && tl > 0) {
      const int tw = tl - 32;
#pragma unroll
      for (int it = 0; it < 3; ++it) {
        const int slt = it * 512 + tid;
        if (slt < 1280) {
          const int r = (int)(((unsigned)slt * 1639u) >> 16);   // slt/40
          const int j = slt - r * 40;
          const int sp = c0 * CT + tw + r;
          const int ttp = dir ? ((sp < len) ? (len - 1 - sp) : sp) : sp;
          f16x8 v = *(const f16x8*)&hstage[((tw + r) & 63) * 320 + j * 8];
          *(f16x8*)&xnext[(size_t)(b * 1024 + ttp) * 640 + dir * 320 + j * 8] = v;
        }
      }
    }
    __syncthreads();                              // B1: ylds ready

    if (tid < 320) {
      const int u = tid;
      float pi = ssl[u]       * (float)ylds[u]       + gxi + bsl[u];
      float pf = ssl[u + 320] * (float)ylds[u + 320] + gxf + bsl[u + 320];
      float pg = ssl[u + 640] * (float)ylds[u + 640] + gxg + bsl[u + 640];
      float po = ssl[u + 960] * (float)ylds[u + 960] + gxo + bsl[u + 960];
      float ig = fsigm(pi);
      float fg = fsigm(pf);
      float gg = ftanh(pg);
      float og = fsigm(po);
      c_state = fg * c_state + ig * gg;
      float hv = og * ftanh(c_state);
      hstage[(tl & 63) * 320 + u] = (f16)hv;
      ((uint8_t*)hqw)[u] = (uint8_t)(int8_t)(int)rintf(hv * 127.f);
    }
    __syncthreads();                              // B2: hqw ready for next dot

    gxi = nxi; gxf = nxf; gxg = nxg; gxo = nxo;
  }

  {
    const int tw = CT - 32;
#pragma unroll
    for (int it = 0; it < 3; ++it) {
      const int slt = it * 512 + tid;
      if (slt < 1280) {
        const int r = (int)(((unsigned)slt * 1639u) >> 16);
        const int j = slt - r * 40;
        const int sp = c0 * CT + tw + r;
        const int ttp = dir ? ((sp < len) ? (len - 1 - sp) : sp) : sp;
        f16x8 v = *(const f16x8*)&hstage[((tw + r) & 63) * 320 + j * 8];
        *(f16x8*)&xnext[(size_t)(b * 1024 + ttp) * 640 + dir * 320 + j * 8] = v;
      }
    }
  }
  if (tid < 320) {
    hsave[wg * 320 + tid] = hstage[63 * 320 + tid];
    csave[wg * 320 + tid] = c_state;
  }
}

// ---------------------- projection GEMM (f32 out) --------------------------
__global__ __launch_bounds__(256)
void gemm_proj(const f16* __restrict__ A, const f16* __restrict__ W,
               float* __restrict__ outf, int lda, int kTiles, int ldo) {
  __shared__ __align__(16) f16 As[128 * 32];
  __shared__ __align__(16) f16 Ws[128 * 32];
  const int tid = threadIdx.x;
  const int lane = tid & 63, wid = tid >> 6;
  const int wm = wid >> 1, wn = wid & 1;
  const int m0 = blockIdx.y * 128, n0 = blockIdx.x * 128;
  const int r_base = lane >> 2;
  const int chs = ((((lane & 3) + (r_base >> 1)) & 3)) * 8;  // swizzled SRC chunk

  f32x4 acc[4][4] = {};

  for (int kt = 0; kt < kTiles; ++kt) {
    const int k0 = kt * 32;
    __syncthreads();
#pragma unroll
    for (int hh = 0; hh < 2; ++hh) {
      const int c = wid * 2 + hh;
      stage16(&As[c * 512], A + (size_t)(m0 + c * 16 + r_base) * lda + k0 + chs);
      stage16(&Ws[c * 512], W + (size_t)(n0 + c * 16 + r_base) * lda + k0 + chs);
    }
    __syncthreads();

    const int q = lane >> 4;
    const int l15 = lane & 15;
    const int cs = (q - (l15 >> 1)) & 3;
    const int rofs = l15 * 32 + cs * 8;
    f16x8 av[4], wv[4];
#pragma unroll
    for (int i = 0; i < 4; ++i)
      av[i] = *(const f16x8*)&As[(wm * 4 + i) * 512 + rofs];
#pragma unroll
    for (int i = 0; i < 4; ++i)
      wv[i] = *(const f16x8*)&Ws[(wn * 4 + i) * 512 + rofs];
#pragma unroll
    for (int i = 0; i < 4; ++i)
#pragma unroll
      for (int j = 0; j < 4; ++j)
        acc[i][j] = __builtin_amdgcn_mfma_f32_16x16x32_f16(av[i], wv[j], acc[i][j], 0, 0, 0);
  }

  const int r0 = (lane >> 4) * 4, cn = lane & 15;
#pragma unroll
  for (int i = 0; i < 4; ++i) {
    const int m = m0 + wm * 64 + i * 16 + r0;
#pragma unroll
    for (int j = 0; j < 4; ++j) {
      const int n = n0 + wn * 64 + j * 16 + cn;
#pragma unroll
      for (int r = 0; r < 4; ++r)
        outf[(size_t)(m + r) * ldo + n] = acc[i][j][r];
    }
  }
}

// ------------------------- logsumexp over K=72 ------------------------------
__global__ void lse_kernel(const float* __restrict__ Z, const float* __restrict__ b_lin,
                           float* __restrict__ lseout) {
  int row = blockIdx.x * 4 + (threadIdx.x >> 6);
  int l = threadIdx.x & 63;
  const float* z = Z + (size_t)row * 128;
  float v0 = (l < 72) ? z[l] + b_lin[l] : NEGF;
  float v1 = (l < 8) ? z[l + 64] + b_lin[l + 64] : NEGF;
  float m = fmaxf(v0, v1);
#pragma unroll
  for (int o = 32; o; o >>= 1) m = fmaxf(m, __shfl_xor(m, o, 64));
  float s = ((l < 72) ? __expf(v0 - m) : 0.f) + ((l < 8) ? __expf(v1 - m) : 0.f);
#pragma unroll
  for (int o = 32; o; o >>= 1) s += __shfl_xor(s, o, 64);
  if (l == 0) lseout[row] = m + __logf(s);
}

// --------------- emission pre-gather: emc[b][t][s] (f16) -------------------
// emc = (Z[t][ext[s]] + b_lin[ext[s]] - lse[t]) * log2(e).  Base-2 domain so
// the ctc recursion uses raw v_exp_f32 / v_log_f32.
__global__ void emz_kernel(const float* __restrict__ Z, const float* __restrict__ lse,
                           const float* __restrict__ b_lin,
                           const int* __restrict__ labels,
                           f16* __restrict__ emc) {
  const int b = blockIdx.y;
  const int t0 = blockIdx.x * 4;
  const int tid = threadIdx.x;   // 256
  __shared__ int ext[200];
  __shared__ float bls[200];
  if (tid < 200) {
    int e = (tid < 193 && (tid & 1)) ? labels[b * 96 + (tid >> 1)] : 0;
    ext[tid] = e;
    bls[tid] = b_lin[e];
  }
  __syncthreads();
#pragma unroll
  for (int dt = 0; dt < 4; ++dt) {
    const int t = t0 + dt;
    const float lst = lse[b * 1024 + t];
    const float* zr = Z + ((size_t)(b * 1024 + t)) * 128;
    for (int s = tid; s < 200; s += 256)
      emc[((size_t)(b * 1024 + t)) * 200 + s] =
          (f16)((zr[ext[s]] + bls[s] - lst) * 1.4426950408889634f);
  }
}

// ------------------------------ CTC forward ---------------------------------
__global__ void ctc_kernel(const f16* __restrict__ emc,
                           const int* __restrict__ labels, const int* __restrict__ inlen,
                           const int* __restrict__ lablen, float* __restrict__ num) {
  const int b = blockIdx.x;
  const int lane = threadIdx.x;          // 64
  __shared__ int ext[200];
  __shared__ float afin[200];

  for (int s = lane; s < 200; s += 64)
    ext[s] = (s < 193 && (s & 1)) ? labels[b * 96 + (s >> 1)] : 0;
  __syncthreads();

  const int L = lablen[b], len = inlen[b];
  const int Send = 2 * L + 1;
  const f16* eb = emc + (size_t)b * 1024 * 200;

  float a[4];
  bool  skp[4], val[4];
#pragma unroll
  for (int j = 0; j < 4; ++j) {
    const int s = lane * 4 + j;
    val[j] = (s < Send) && (s < 193);
    skp[j] = (s < 193) && (s & 1) && (s >= 2) && (ext[s] != ext[s - 2]);
  }
  {
    f16x4v e0 = *(const f16x4v*)&eb[lane * 4];   // t = 0
#pragma unroll
    for (int j = 0; j < 4; ++j) {
      const int s = lane * 4 + j;
      a[j] = (s <= 1 && val[j]) ? (float)e0[j] : NEGF;
    }
  }

  auto step = [&](f16x4v ev) {
    float p3 = __shfl_up(a[3], 1, 64);
    float p2 = __shfl_up(a[2], 1, 64);
    if (lane == 0) { p3 = NEGF; p2 = NEGF; }
    const float x2[4] = {p3, a[0], a[1], a[2]};
    const float x3[4] = {p2, p3, a[0], a[1]};
#pragma unroll
    for (int j = 0; j < 4; ++j) {
      const float xa = a[j], xb = x2[j];
      const float xc = skp[j] ? x3[j] : NEGF;
      const float m = fmaxf(xa, fmaxf(xb, xc));
      const float sum = fexp2(xa - m) + fexp2(xb - m) + fexp2(xc - m);
      const float nv = m + flog2(sum) + (float)ev[j];
      a[j] = val[j] ? nv : NEGF;
    }
  };

  // depth-8 register ring, fully static slot indexing
  f16x4v ring[8];
#pragma unroll
  for (int d = 1; d <= 8; ++d) {
    const int r = (d < len) ? d : (len - 1);
    ring[d & 7] = *(const f16x4v*)&eb[(size_t)r * 200 + lane * 4];
  }

  int t = 1;
  for (; t + 8 <= len; t += 8) {
#pragma unroll
    for (int k = 0; k < 8; ++k) {
      const int slot = (1 + k) & 7;        // t == 1 (mod 8)
      f16x4v ev = ring[slot];
      const int tp = t + k + 8;
      if (tp < len)
        ring[slot] = *(const f16x4v*)&eb[(size_t)tp * 200 + lane * 4];
      step(ev);
    }
  }
  for (; t < len; ++t)
    step(*(const f16x4v*)&eb[(size_t)t * 200 + lane * 4]);

#pragma unroll
  for (int j = 0; j < 4; ++j) {
    const int s = lane * 4 + j;
    if (s < 193) afin[s] = a[j];
  }
  __syncthreads();
  if (lane == 0) {
    const float aL = afin[2 * L], aLm1 = afin[2 * L - 1];
    const float m = fmaxf(aL, aLm1);
    // back to natural log for the final reduction
    num[b] = 0.6931471805599453f * (m + flog2(fexp2(aL - m) + fexp2(aLm1 - m)));
  }
}

__global__ void final_kernel(const float* __restrict__ num, float* __restrict__ out) {
  int l = threadIdx.x;  // 64
  float v = -1.1f * num[l];
#pragma unroll
  for (int o = 32; o; o >>= 1) v += __shfl_xor(v, o, 64);
  if (l == 0) out[0] = v * (1.f / 64.f);
}

__global__ void sentinel_kernel(float* __restrict__ out, float code) { out[0] = code; }

// ------------------------------ launcher ------------------------------------
extern "C" void kernel_launch(void* const* d_in, const int* in_sizes, int n_in,
                              void* d_out, int out_size, void* d_ws, size_t ws_size,
                              hipStream_t stream) {
  (void)in_sizes; (void)n_in; (void)out_size;

  const float* logits   = (const float*)d_in[0];
  const int*   labels   = (const int*)d_in[1];
  const int*   in_lens  = (const int*)d_in[2];
  const int*   lab_lens = (const int*)d_in[3];
  const float* Wih0     = (const float*)d_in[4];
  const float* Whh0     = (const float*)d_in[5];
  const float* b0       = (const float*)d_in[6];
  const float* Wih      = (const float*)d_in[7];
  const float* Whh      = (const float*)d_in[8];
  const float* bb       = (const float*)d_in[9];
  const float* W_lin    = (const float*)d_in[10];
  const float* b_lin    = (const float*)d_in[11];

  const size_t NEED = (size_t)224 * 1024 * 1024;
  if (ws_size < NEED) {
    sentinel_kernel<<<1, 1, 0, stream>>>((float*)d_out, -(float)(ws_size >> 20));
    return;
  }

  char* ws = (char*)d_ws;
  size_t off = 0;
  auto alloc = [&](size_t bytes) -> char* {
    char* p = ws + off;
    off += (bytes + 255) & ~(size_t)255;
    return p;
  };
  f16*      Xa     = (f16*)alloc((size_t)65536 * 640 * 2);        // 83.9 MB
  f16*      Xb     = (f16*)alloc((size_t)65536 * 640 * 2);        // 83.9 MB
  f16*      gxc    = (f16*)alloc((size_t)2 * 64 * CT * 1280 * 2); // 41.9 MB
  f16*      Wt0    = (f16*)alloc((size_t)2560 * 128 * 2);
  f16*      Wt12   = (f16*)alloc((size_t)2 * 2560 * 640 * 2);
  f16*      WtL    = (f16*)alloc((size_t)128 * 640 * 2);
  uint32_t* wqi    = (uint32_t*)alloc((size_t)6 * 10 * 20 * 512 * 4);  // 2.46 MB
  float*    scales = (float*)alloc((size_t)6 * 1280 * 4);
  float*    lseb   = (float*)alloc((size_t)65536 * 4);
  float*    num    = (float*)alloc(64 * 4);
  f16*      hsave  = (f16*)alloc((size_t)128 * 320 * 2);
  float*    csave  = (float*)alloc((size_t)128 * 320 * 4);
  // aliases (disjoint lifetimes)
  f16*      A0     = Xb;           // dead after layer 0; Xb first written layer 1
  float*    Z      = (float*)gxc;  // gxc dead after layer-2 scan
  f16*      emc    = Xa;           // Xa dead after gemm_proj

  conv_logits<<<32768, 256, 0, stream>>>(logits, A0);
  conv_wt0<<<1280, 256, 0, stream>>>(Wih0, Wt0);
  conv_copy<<<12800, 256, 0, stream>>>(Wih, Wt12, 3276800);
  conv_wtl<<<320, 256, 0, stream>>>(W_lin, WtL);
  conv_scale<<<1920, 256, 0, stream>>>(Whh0, Whh, scales);
  conv_wq<<<2400, 256, 0, stream>>>(Whh0, Whh, scales, wqi);

  // layer 0: A0 -> Xa
  for (int c = 0; c < 1024 / CT; ++c) {
    gemm_chunk<<<dim3(5, 128), 256, 0, stream>>>(A0, Wt0, gxc, in_lens, 128, 4, c);
    lstm_scan_chunk<<<128, 512, 0, stream>>>(wqi, scales, gxc, b0, in_lens, Xa,
                                             hsave, csave, 0, c);
  }
  // layer 1: Xa -> Xb
  for (int c = 0; c < 1024 / CT; ++c) {
    gemm_chunk<<<dim3(5, 128), 256, 0, stream>>>(Xa, Wt12, gxc, in_lens, 640, 20, c);
    lstm_scan_chunk<<<128, 512, 0, stream>>>(wqi, scales, gxc, bb, in_lens, Xb,
                                             hsave, csave, 1, c);
  }
  // layer 2: Xb -> Xa
  for (int c = 0; c < 1024 / CT; ++c) {
    gemm_chunk<<<dim3(5, 128), 256, 0, stream>>>(Xb, Wt12 + (size_t)2560 * 640, gxc,
                                                 in_lens, 640, 20, c);
    lstm_scan_chunk<<<128, 512, 0, stream>>>(wqi, scales, gxc, bb + 2560, in_lens, Xa,
                                             hsave, csave, 2, c);
  }
  // projection: Xa -> Z (f32)
  gemm_proj<<<dim3(1, 512), 256, 0, stream>>>(Xa, WtL, Z, 640, 20, 128);

  lse_kernel<<<16384, 256, 0, stream>>>(Z, b_lin, lseb);
  emz_kernel<<<dim3(256, 64), 256, 0, stream>>>(Z, lseb, b_lin, labels, emc);
  ctc_kernel<<<64, 64, 0, stream>>>(emc, labels, in_lens, lab_lens, num);
  final_kernel<<<1, 64, 0, stream>>>(num, (float*)d_out);
}